// Round 6
// baseline (230.326 us; speedup 1.0000x reference)
//
#include <hip/hip_runtime.h>
#include <hip/hip_bf16.h>

// Problem constants
#define NN 8192
#define DD 128
#define CC 1000
#define LN2 0.69314718f
#define G_SCALE 14.42695041f   // 10/ln2 : MFMA emits log2-domain scores
#define NSTRIP 32
#define JPER   256             // 8192/32 j-columns per strip
#define NTILE  4               // JPER/64
#define LROW   132             // u16 per LDS B-row: 264 B = 66 dw === 2 mod 32
                               // -> ds_read_b128 start banks 2*lcol (16 distinct,
                               //    2 lanes/bank) = conflict-free per m136

typedef short v8s __attribute__((ext_vector_type(8)));
typedef float v4f __attribute__((ext_vector_type(4)));
typedef unsigned short u16;
typedef unsigned int u32;

#if __has_builtin(__builtin_amdgcn_exp2f)
#define EXP2(x) __builtin_amdgcn_exp2f(x)
#else
#define EXP2(x) exp2f(x)
#endif
#if __has_builtin(__builtin_amdgcn_logf)
#define LOG2(x) __builtin_amdgcn_logf(x)
#else
#define LOG2(x) log2f(x)
#endif

// ---- helpers -------------------------------------------------------------
static __device__ __forceinline__ float bf2f(u16 u) {
    union { float f; u32 i; } x; x.i = ((u32)u) << 16; return x.f;
}
static __device__ __forceinline__ u16 f2bf(float f) {
    u32 x = __float_as_uint(f);
    return (u16)((x + 0x7FFFu + ((x >> 16) & 1u)) >> 16);  // RNE
}
static __device__ __forceinline__ float wsum(float v) {
    #pragma unroll
    for (int m = 1; m < 64; m <<= 1) v += __shfl_xor(v, m, 64);
    return v;
}
static __device__ __forceinline__ float wmax(float v) {
    #pragma unroll
    for (int m = 1; m < 64; m <<= 1) v = fmaxf(v, __shfl_xor(v, m, 64));
    return v;
}

// ---- prep ----------------------------------------------------------------
// Blocks [0, 8192): 2 feature rows each (256 thr, 128 per row).
// Blocks [8192, 8224): decode 256 targets each + global histogram atomics.
// (counts/sums/P/Q/S zeroed by hipMemsetAsync before this launch.)
__global__ __launch_bounds__(256) void prep_kernel(const void* __restrict__ fs,
                                                   const void* __restrict__ ft,
                                                   const int* __restrict__ traw,
                                                   u16* __restrict__ f1, u16* __restrict__ f2,
                                                   int* __restrict__ tgt32,
                                                   int* __restrict__ counts) {
    int b = blockIdx.x, tid = threadIdx.x;
    if (b < 8192) {
        int half = tid >> 7;          // 0..1 : which row of the pair
        int col = tid & 127;
        const void* src; u16* dst; float gain; int row;
        if (b < 4096) { src = fs; dst = f1; gain = G_SCALE; row = b * 2 + half; }
        else          { src = ft; dst = f2; gain = 1.0f;    row = (b - 4096) * 2 + half; }
        // dtype detect: u32 words at bf16-interp offsets (in-bounds both ways);
        // each wave is entirely within one row -> wave ballot is per-row.
        u32 wb = ((const u32*)src)[(size_t)row * 64 + (tid & 63)];
        unsigned e = (wb >> 7) & 0xFF;
        int isF32 = (__popcll(__ballot(e >= 100 && e <= 140)) < 32);
        float x = isF32 ? ((const float*)src)[(size_t)row * DD + col]
                        : bf2f(((const u16*)src)[(size_t)row * DD + col]);
        float ss = x * x;
        #pragma unroll
        for (int m = 1; m < 64; m <<= 1) ss += __shfl_xor(ss, m, 64);
        __shared__ float sb[4];
        if ((tid & 63) == 0) sb[tid >> 6] = ss;
        __syncthreads();
        float tot = half ? (sb[2] + sb[3]) : (sb[0] + sb[1]);
        float sc = gain / fmaxf(sqrtf(tot), 1e-12f);
        dst[(size_t)row * DD + col] = f2bf(x * sc);
    } else {
        int db = b - 8192;                      // 0..31
        int idx = db * 256 + tid;               // target index 0..8191
        // int64-vs-int32 detect on odd dwords, in-bounds under both widths
        int k = db * 128 + (tid & 127);         // < 4096
        int odd = traw[2 * k + 1];
        int is32 = (__ballot(odd != 0) != 0ull);
        int t = (is32 ? traw[idx] : traw[2 * idx]) & 127;
        tgt32[idx] = t;
        atomicAdd(&counts[t], 1);
    }
}

// ---- fused JSD (blocks < 2048) + NCE (blocks >= 2048) --------------------
// NCE: block = 128 i-rows x 256 j-strip. B staged in single padded LDS
// buffer; next tile's global load carried in registers across the barrier.
// Per row accumulate P = sum_j 2^s2, Q = sum_pos 2^s2, S = sum_pos s2,
// atomically added into per-row global accumulators.
__global__ __launch_bounds__(256) void main_kernel(const u16* __restrict__ f1,
                                                   const u16* __restrict__ f2,
                                                   const int* __restrict__ tgt,
                                                   const void* __restrict__ ls,
                                                   const void* __restrict__ lt,
                                                   float* __restrict__ Pp,
                                                   float* __restrict__ Qp,
                                                   float* __restrict__ Sp,
                                                   float* __restrict__ sums) {
    __shared__ u16 lds[64 * LROW];   // 16896 B
    int bx = blockIdx.x;
    int tid = threadIdx.x;
    int w = tid >> 6, lane = tid & 63;

    if (bx >= NN / 4) {
        // ------------------- NCE path -------------------
        int nb = bx - NN / 4;
        int strip = nb & 31;
        int ib = nb >> 5;
        int quad = lane >> 4, lcol = lane & 15;
        int ibase = ib * 128 + w * 32;

        // A fragments for this wave's 32 rows, held across the j-loop
        v8s a0[4], a1[4];
        #pragma unroll
        for (int t = 0; t < 4; t++) {
            int k = t * 32 + quad * 8;
            a0[t] = *(const v8s*)(f1 + (size_t)(ibase + lcol) * DD + k);
            a1[t] = *(const v8s*)(f1 + (size_t)(ibase + 16 + lcol) * DD + k);
        }
        int ti[8];
        #pragma unroll
        for (int a = 0; a < 2; a++)
            #pragma unroll
            for (int v = 0; v < 4; v++)
                ti[a * 4 + v] = tgt[ibase + a * 16 + quad * 4 + v];

        float P[8] = {}, Q[8] = {}, S[8] = {};

        // staging geometry: 256 thr x 4 rounds x 16 B = 16 KB tile
        int srow = tid >> 4;           // 0..15
        int schunk = tid & 15;         // 0..15
        const u16* gb = f2 + (size_t)strip * JPER * DD;

        float4 st[4];
        #pragma unroll
        for (int r = 0; r < 4; r++)
            st[r] = *(const float4*)(gb + (size_t)(r * 16 + srow) * DD + schunk * 8);

        for (int it = 0; it < NTILE; ++it) {
            if (it) __syncthreads();   // previous tile's LDS reads complete
            #pragma unroll
            for (int r = 0; r < 4; r++)
                *(float4*)(lds + (r * 16 + srow) * LROW + schunk * 8) = st[r];
            __syncthreads();
            if (it + 1 < NTILE) {     // prefetch next tile; latency hidden by compute
                const u16* g2 = gb + (size_t)(it + 1) * 64 * DD;
                #pragma unroll
                for (int r = 0; r < 4; r++)
                    st[r] = *(const float4*)(g2 + (size_t)(r * 16 + srow) * DD + schunk * 8);
            }
            int jb = strip * JPER + it * 64;
            int tj0 = tgt[jb + lcol];
            int tj1 = tgt[jb + 16 + lcol];
            int tj2 = tgt[jb + 32 + lcol];
            int tj3 = tgt[jb + 48 + lcol];

            const u16* lb = lds + lcol * LROW + quad * 8;
            v4f zero = {0.f, 0.f, 0.f, 0.f};
            v4f acc[8] = {zero, zero, zero, zero, zero, zero, zero, zero};
            #pragma unroll
            for (int t = 0; t < 4; t++) {
                v8s b0 = *(const v8s*)(lb + 0 * 16 * LROW + t * 32);
                v8s b1 = *(const v8s*)(lb + 1 * 16 * LROW + t * 32);
                v8s b2 = *(const v8s*)(lb + 2 * 16 * LROW + t * 32);
                v8s b3 = *(const v8s*)(lb + 3 * 16 * LROW + t * 32);
                acc[0] = __builtin_amdgcn_mfma_f32_16x16x32_bf16(a0[t], b0, acc[0], 0, 0, 0);
                acc[1] = __builtin_amdgcn_mfma_f32_16x16x32_bf16(a0[t], b1, acc[1], 0, 0, 0);
                acc[2] = __builtin_amdgcn_mfma_f32_16x16x32_bf16(a0[t], b2, acc[2], 0, 0, 0);
                acc[3] = __builtin_amdgcn_mfma_f32_16x16x32_bf16(a0[t], b3, acc[3], 0, 0, 0);
                acc[4] = __builtin_amdgcn_mfma_f32_16x16x32_bf16(a1[t], b0, acc[4], 0, 0, 0);
                acc[5] = __builtin_amdgcn_mfma_f32_16x16x32_bf16(a1[t], b1, acc[5], 0, 0, 0);
                acc[6] = __builtin_amdgcn_mfma_f32_16x16x32_bf16(a1[t], b2, acc[6], 0, 0, 0);
                acc[7] = __builtin_amdgcn_mfma_f32_16x16x32_bf16(a1[t], b3, acc[7], 0, 0, 0);
            }
            #pragma unroll
            for (int a = 0; a < 2; a++) {
                #pragma unroll
                for (int v = 0; v < 4; v++) {
                    int t_i = ti[a * 4 + v];
                    #pragma unroll
                    for (int jf = 0; jf < 4; jf++) {
                        float s2 = acc[a * 4 + jf][v];
                        float e1 = EXP2(s2);
                        int tj = (jf == 0) ? tj0 : (jf == 1) ? tj1 : (jf == 2) ? tj2 : tj3;
                        bool pos = (tj == t_i);
                        P[a * 4 + v] += e1;
                        Q[a * 4 + v] += pos ? e1 : 0.0f;
                        S[a * 4 + v] += pos ? s2 : 0.0f;
                    }
                }
            }
        }

        // reduce each row across its 16 lanes, atomic-accumulate per-row
        #pragma unroll
        for (int a = 0; a < 2; a++) {
            #pragma unroll
            for (int v = 0; v < 4; v++) {
                float p = P[a * 4 + v], q = Q[a * 4 + v], s = S[a * 4 + v];
                #pragma unroll
                for (int m = 1; m < 16; m <<= 1) {
                    p += __shfl_xor(p, m, 64);
                    q += __shfl_xor(q, m, 64);
                    s += __shfl_xor(s, m, 64);
                }
                if (lcol == 0) {
                    int row = ibase + a * 16 + quad * 4 + v;
                    atomicAdd(&Pp[row], p);
                    atomicAdd(&Qp[row], q);
                    atomicAdd(&Sp[row], s);
                }
            }
        }
    } else {
        // ------------------- JSD path (wave per row) -------------------
        int row = bx * 4 + w;
        u32 wb = ((const u32*)ls)[(size_t)row * 500 + lane];
        unsigned e = (wb >> 7) & 0xFF;
        int isF32 = (__popcll(__ballot(e >= 100 && e <= 140)) < 32);

        float xs[16], xt[16];
        #pragma unroll
        for (int c = 0; c < 4; c++) {
            int idx = c * 256 + lane * 4;
            if (idx < CC) {
                if (isF32) {
                    float4 a = *(const float4*)((const float*)ls + (size_t)row * CC + idx);
                    float4 b = *(const float4*)((const float*)lt + (size_t)row * CC + idx);
                    xs[c*4+0] = a.x; xs[c*4+1] = a.y; xs[c*4+2] = a.z; xs[c*4+3] = a.w;
                    xt[c*4+0] = b.x; xt[c*4+1] = b.y; xt[c*4+2] = b.z; xt[c*4+3] = b.w;
                } else {
                    ushort4 a = *(const ushort4*)((const u16*)ls + (size_t)row * CC + idx);
                    ushort4 b = *(const ushort4*)((const u16*)lt + (size_t)row * CC + idx);
                    xs[c*4+0] = bf2f(a.x); xs[c*4+1] = bf2f(a.y); xs[c*4+2] = bf2f(a.z); xs[c*4+3] = bf2f(a.w);
                    xt[c*4+0] = bf2f(b.x); xt[c*4+1] = bf2f(b.y); xt[c*4+2] = bf2f(b.z); xt[c*4+3] = bf2f(b.w);
                }
            } else {
                #pragma unroll
                for (int q = 0; q < 4; q++) { xs[c*4+q] = -1e30f; xt[c*4+q] = -1e30f; }
            }
        }
        float ms = -1e30f, mt = -1e30f;
        #pragma unroll
        for (int q = 0; q < 16; q++) { ms = fmaxf(ms, xs[q]); mt = fmaxf(mt, xt[q]); }
        ms = wmax(ms); mt = wmax(mt);
        float es = 0.f, et = 0.f;
        #pragma unroll
        for (int q = 0; q < 16; q++) { es += __expf(xs[q] - ms); et += __expf(xt[q] - mt); }
        es = wsum(es); et = wsum(et);
        float lse_s = ms + __logf(es), lse_t = mt + __logf(et);
        float contrib = 0.f;
        #pragma unroll
        for (int q = 0; q < 16; q++) {
            float lps = xs[q] - lse_s, lpt = xt[q] - lse_t;
            contrib += (lpt - lps) * (__expf(lpt) - __expf(lps));
        }
        contrib = wsum(contrib);
        float* sh = (float*)lds;
        if (lane == 0) sh[w] = contrib;
        __syncthreads();
        if (tid == 0) atomicAdd(&sums[1], sh[0] + sh[1] + sh[2] + sh[3]);
    }
}

// ---- rowred + finalize ---------------------------------------------------
// 32 blocks x 256, one row per thread: per-row NCE loss from accumulated
// P/Q/S; last block (device done-counter) writes the dual-format output.
__global__ __launch_bounds__(256) void rowred_kernel(const float* __restrict__ Pp,
                                                     const float* __restrict__ Qp,
                                                     const float* __restrict__ Sp,
                                                     const int* __restrict__ tgt,
                                                     const int* __restrict__ counts,
                                                     float* __restrict__ sums,
                                                     u32* __restrict__ out) {
    __shared__ float sb[4];
    int tid = threadIdx.x;
    int i = blockIdx.x * 256 + tid;
    float P = Pp[i], Q = Qp[i], S = Sp[i];
    int cnt = counts[tgt[i]];
    float pos = LN2 * LOG2(P) - LN2 * S / (float)cnt;
    float neg = (1.0f - Q / P) / (float)(NN - cnt);
    float l = wsum(pos + neg);
    if ((tid & 63) == 0) sb[tid >> 6] = l;
    __syncthreads();
    if (tid == 0) {
        atomicAdd(&sums[0], sb[0] + sb[1] + sb[2] + sb[3]);
        __threadfence();
        int* done = (int*)(sums + 2);
        if (atomicAdd(done, 1) == 31) {
            float Lsum = atomicAdd(&sums[0], 0.0f);   // device-scope read
            float Jsum = atomicAdd(&sums[1], 0.0f);
            float loss = (Lsum + 0.5f * Jsum) / (float)NN;
            u32 fb = __float_as_uint(loss);
            out[0] = (fb & 0xFFFF0000u) | (u32)f2bf(loss);
        }
    }
}

// ---- launch --------------------------------------------------------------
extern "C" void kernel_launch(void* const* d_in, const int* in_sizes, int n_in,
                              void* d_out, int out_size, void* d_ws, size_t ws_size,
                              hipStream_t stream) {
    const void* fs = d_in[0];
    const void* ft = d_in[1];
    const void* ls = d_in[2];
    const void* lt = d_in[3];
    const int* tgt_raw = (const int*)d_in[4];

    char* wsp = (char*)d_ws;
    u16*   f1     = (u16*)(wsp + 0);           // 2 MiB
    u16*   f2     = (u16*)(wsp + 2097152);     // 2 MiB
    float* Pp     = (float*)(wsp + 4194304);   // 32 KiB  -- zeroed
    float* Qp     = (float*)(wsp + 4227072);   // 32 KiB  -- zeroed
    float* Sp     = (float*)(wsp + 4259840);   // 32 KiB  -- zeroed
    int*   counts = (int*)(wsp + 4292608);     // 512 B   -- zeroed
    float* sums   = (float*)(wsp + 4293120);   // 16 B    -- zeroed (Lsum,Jsum,done)
    int*   tgt32  = (int*)(wsp + 4293136 + 240);  // 32 KiB (aligned region after)

    hipMemsetAsync(wsp + 4194304, 0, 98832, stream);  // Pp..sums contiguous
    prep_kernel<<<8192 + 32, 256, 0, stream>>>(fs, ft, tgt_raw, f1, f2, tgt32, counts);
    main_kernel<<<NN / 4 + NSTRIP * 64, 256, 0, stream>>>(f1, f2, tgt32, ls, lt,
                                                          Pp, Qp, Sp, sums);
    rowred_kernel<<<32, 256, 0, stream>>>(Pp, Qp, Sp, tgt32, counts, sums, (u32*)d_out);
}